// Round 4
// baseline (142.824 us; speedup 1.0000x reference)
//
#include <hip/hip_runtime.h>

// Sizes (fixed by the reference)
#define Bq 32
#define Gq 16
#define Oq 256
#define Nq 88
#define Tq 256

typedef short bf16x8 __attribute__((ext_vector_type(8)));   // 8 bf16 in 4 VGPRs
typedef short bf16x4 __attribute__((ext_vector_type(4)));   // 4 bf16 in 2 VGPRs
typedef float f32x4 __attribute__((ext_vector_type(4)));

static __device__ __forceinline__ short f2bf(float f) {
    return __builtin_bit_cast(short, (__bf16)f);  // RNE convert, bits as short
}

static __device__ __forceinline__ void gld_lds16(const float* src, float* lds_dst) {
    __builtin_amdgcn_global_load_lds(
        (const __attribute__((address_space(1))) void*)src,
        (__attribute__((address_space(3))) void*)lds_dst, 16, 0, 0);
}

// out[b,n,o] = bias[o]  (pre-init for the atomic g-reduction)
__global__ __launch_bounds__(256)
void mlm_init(const float* __restrict__ bias, float* __restrict__ out) {
    const int idx = blockIdx.x * 256 + threadIdx.x;   // 720896 = 2816*256 exact
    out[idx] = bias[idx & (Oq - 1)];
}

// x -> bf16 bit pattern (ws scratch); read 256x by the main kernel from L2/L3
__global__ __launch_bounds__(256)
void mlm_xcvt(const float* __restrict__ x, short* __restrict__ xbf) {
    const int idx = blockIdx.x * 256 + threadIdx.x;
    xbf[idx] = f2bf(x[idx]);
}

// Block = (o-tile of 16, ONE g, n-quad of 4). Grid 16*16*22 = 5632, nq fastest
// so co-resident siblings of an (ot,g) group sweep each 88KB (g,o)-row jointly.
// w staged as 16 rows x 4KB CONTIGUOUS bursts (n-adjacent) -> sequential DRAM
// streams (vs R2/R3's 1-2KB pieces at 23MB g-jumps = dead row-buffer locality).
// g-reduction via f32 atomicAdd onto bias-initialized out; y[b,g] applied to
// the f32 partial before the cross-wave reduce (same numerics as R2).
template <bool XBF>
__global__ __launch_bounds__(256, 2)
void mlm_split(const float* __restrict__ x, const short* __restrict__ xbf,
               const float* __restrict__ y,
               const float* __restrict__ w, const float* __restrict__ mask,
               float* __restrict__ out) {
    __shared__ float wslab[16][4][256];   // 64 KB: [o-row][nn][t]; red overlay later

    const int bid = blockIdx.x;
    const int nq = bid % 22;
    const int gg = (bid / 22) & 15;
    const int ot = bid / (22 * 16);
    const int o0 = ot << 4;
    const int n0 = nq << 2;

    const int tid = threadIdx.x;
    const int wv = tid >> 6;          // 0..3 -> t-window [wv*64, wv*64+64)
    const int lane = tid & 63;
    const int lo = lane & 15;         // A row-slot / B col (o) / C col
    const int hi = lane >> 4;         // k-group 0..3
    const int sr = lo & 7;            // read-side swizzle key (o-row = lo)

    // ---- stage w[gg, o0:o0+16, n0:n0+4, :]: wave wv stages rows wv*4+q,
    //      r-outer / nn-inner -> one 4 KB contiguous run per row.
#pragma unroll
    for (int q = 0; q < 4; ++q) {
        const int r = wv * 4 + q;
        const float* rowp = w + (((size_t)(gg * Oq + o0 + r)) * Nq + n0) * Tq
                              + ((lane ^ (r & 7)) << 2);
#pragma unroll
        for (int nn = 0; nn < 4; ++nn)
            gld_lds16(rowp + nn * Tq, &wslab[r][nn][0]);
    }

    // ---- build A fragments + mask chunks while the slab flies
    // sigma: frag elem (hi,j): j<4 -> t = tA+j ; j>=4 -> t = tA+16+(j-4)
    bf16x8 afr[4][2][2];   // [nn][half][W]
    f32x4 mka[2], mkb[2];
#pragma unroll
    for (int W = 0; W < 2; ++W) {
        const int tA = wv * 64 + W * 32 + hi * 4;
        const int tB = tA + 16;
        mka[W] = *(const f32x4*)(mask + (size_t)(o0 + lo) * Tq + tA);
        mkb[W] = *(const f32x4*)(mask + (size_t)(o0 + lo) * Tq + tB);
#pragma unroll
        for (int nn = 0; nn < 4; ++nn) {
#pragma unroll
            for (int half = 0; half < 2; ++half) {
                const size_t xoff = ((size_t)(half * 16 + lo) * Nq + n0 + nn) * Tq;
                if (XBF) {
                    bf16x4 pa = *(const bf16x4*)(xbf + xoff + tA);
                    bf16x4 pb = *(const bf16x4*)(xbf + xoff + tB);
#pragma unroll
                    for (int j = 0; j < 4; ++j) {
                        afr[nn][half][W][j]     = pa[j];
                        afr[nn][half][W][j + 4] = pb[j];
                    }
                } else {
                    f32x4 xa = *(const f32x4*)(x + xoff + tA);
                    f32x4 xb = *(const f32x4*)(x + xoff + tB);
#pragma unroll
                    for (int j = 0; j < 4; ++j) {
                        afr[nn][half][W][j]     = f2bf(xa[j]);
                        afr[nn][half][W][j + 4] = f2bf(xb[j]);
                    }
                }
            }
        }
    }

    // y[b, gg] for this lane's 8 C rows
    float yv0[4], yv1[4];
#pragma unroll
    for (int i = 0; i < 4; ++i) {
        yv0[i] = y[(hi * 4 + i) * Gq + gg];
        yv1[i] = y[(16 + hi * 4 + i) * Gq + gg];
    }

    asm volatile("s_waitcnt vmcnt(0)" ::: "memory");
    __syncthreads();

    // ---- compute: per wave 2 k-windows, 4 n, 2 b-halves
    f32x4 acc[4][2] = {};
#pragma unroll
    for (int nn = 0; nn < 4; ++nn) {
#pragma unroll
        for (int W = 0; W < 2; ++W) {
            const int c0 = wv * 16 + W * 8 + hi;   // logical 16B-chunk in row
            f32x4 wa4 = *(const f32x4*)&wslab[lo][nn][(c0 ^ sr) << 2];
            f32x4 wb4 = *(const f32x4*)&wslab[lo][nn][((c0 + 4) ^ sr) << 2];
            bf16x8 bfr;
#pragma unroll
            for (int j = 0; j < 4; ++j) {
                bfr[j]     = f2bf(wa4[j] * mka[W][j]);
                bfr[j + 4] = f2bf(wb4[j] * mkb[W][j]);
            }
            acc[nn][0] = __builtin_amdgcn_mfma_f32_16x16x32_bf16(afr[nn][0][W], bfr, acc[nn][0], 0, 0, 0);
            acc[nn][1] = __builtin_amdgcn_mfma_f32_16x16x32_bf16(afr[nn][1][W], bfr, acc[nn][1], 0, 0, 0);
        }
    }

    __syncthreads();   // all waves done reading wslab -> overlay red on it

    // red[wv][nn][b][oo], 32 KB overlay. C layout: col=lane&15, row=(lane>>4)*4+i
    float* red = &wslab[0][0][0];
#pragma unroll
    for (int nn = 0; nn < 4; ++nn) {
#pragma unroll
        for (int i = 0; i < 4; ++i) {
            red[((wv * 4 + nn) * 32 + hi * 4 + i) * 16 + lo]      = yv0[i] * acc[nn][0][i];
            red[((wv * 4 + nn) * 32 + 16 + hi * 4 + i) * 16 + lo] = yv1[i] * acc[nn][1][i];
        }
    }
    __syncthreads();

    // flush: 2048 partial sums (4 nn x 32 b x 16 o), 8 per thread, atomic g-add
#pragma unroll
    for (int s = 0; s < 8; ++s) {
        const int e = s * 256 + tid;
        const int nn = e >> 9;
        const int b  = (e >> 4) & 31;
        const int oo = e & 15;
        float v = 0.f;
#pragma unroll
        for (int p = 0; p < 4; ++p)
            v += red[((p * 4 + nn) * 32 + b) * 16 + oo];
        unsafeAtomicAdd(&out[((size_t)b * Nq + n0 + nn) * Oq + o0 + oo], v);
    }
}

extern "C" void kernel_launch(void* const* d_in, const int* in_sizes, int n_in,
                              void* d_out, int out_size, void* d_ws, size_t ws_size,
                              hipStream_t stream) {
    const float* x    = (const float*)d_in[0];
    const float* y    = (const float*)d_in[1];
    const float* w    = (const float*)d_in[2];
    const float* mask = (const float*)d_in[3];
    const float* bias = (const float*)d_in[4];
    float* out = (float*)d_out;

    const int xelems = Bq * Nq * Tq;                   // 720896
    const bool use_bf = ws_size >= (size_t)xelems * 2; // xbf fits in ws?

    hipLaunchKernelGGL(mlm_init, dim3(xelems / 256), dim3(256), 0, stream, bias, out);

    if (use_bf) {
        short* xbf = (short*)d_ws;
        hipLaunchKernelGGL(mlm_xcvt, dim3(xelems / 256), dim3(256), 0, stream, x, xbf);
        hipLaunchKernelGGL((mlm_split<true>), dim3(16 * 16 * 22), dim3(256), 0, stream,
                           x, xbf, y, w, mask, out);
    } else {
        hipLaunchKernelGGL((mlm_split<false>), dim3(16 * 16 * 22), dim3(256), 0, stream,
                           x, (const short*)nullptr, y, w, mask, out);
    }
}

// Round 5
// 136.537 us; speedup vs baseline: 1.0461x; 1.0461x over previous
//
#include <hip/hip_runtime.h>

// Sizes (fixed by the reference)
#define Bq 32
#define Gq 16
#define Oq 256
#define Nq 88
#define Tq 256

typedef short bf16x8 __attribute__((ext_vector_type(8)));   // 8 bf16 in 4 VGPRs
typedef float f32x4 __attribute__((ext_vector_type(4)));

static __device__ __forceinline__ short f2bf(float f) {
    return __builtin_bit_cast(short, (__bf16)f);  // RNE convert, bits as short
}

// Async global->LDS, 16B per lane. Dest = wave-uniform base + lane*16 (linear).
// Source is per-lane -> swizzle applied on the GLOBAL side (rule 21).
static __device__ __forceinline__ void gld_lds16(const float* src, float* lds_dst) {
    __builtin_amdgcn_global_load_lds(
        (const __attribute__((address_space(1))) void*)src,
        (__attribute__((address_space(3))) void*)lds_dst, 16, 0, 0);
}

// out[b,n,o] = sum_{g,t} x[b,n,t] * y[b,g] * w[g,o,n,t] * mask[o,t] + bias[o]
//
// R2 structure (best so far) + T3/T4 pipeline fix:
//  - TRIPLE-buffered 16KB weight slabs, each wave issues exactly 4
//    global_load_lds per g-iteration.
//  - Counted s_waitcnt vmcnt(4) + RAW s_barrier per iteration (never drain
//    to 0 in the main loop; __syncthreads would emit its own vmcnt(0) drain —
//    that drain was R2's ~20% stall). Prefetch distance = 2 iterations.
//  - All prologue VMEM (x, mask, y) is consumed before the first gld_lds so
//    the per-wave vmcnt count in the loop is exactly {4 issued}/iteration.
//  - XOR swizzle chunk^=(o-row&7) on both global source and LDS read (rule 21).
//  - y[b,g] applied per-g to the f32 MFMA partial (precision + less VALU).
//  - Chunked XCD swizzle (1408%8==0, bijective) for x/mask L2 locality.
__global__ __launch_bounds__(256, 3)
void mlm_mfma5(const float* __restrict__ x, const float* __restrict__ y,
               const float* __restrict__ w, const float* __restrict__ mask,
               const float* __restrict__ bias, float* __restrict__ out) {
    __shared__ float wbuf[3][4096];   // 3 x 16KB: [16 rows(o)][64 chunks x 4 floats]
    __shared__ float y_lds[512];      // y[b][g] row-major

    // XCD chunked swizzle: consecutive swz share n -> same-XCD x/mask reuse
    const int bid = blockIdx.x;
    const int swz = (bid & 7) * ((Nq * 16) / 8) + (bid >> 3);
    const int n  = swz >> 4;          // 0..87
    const int o0 = (swz & 15) << 4;   // o-tile base

    const int tid  = threadIdx.x;
    const int wv   = tid >> 6;        // 0..3 -> t-range [wv*64, wv*64+64)
    const int lane = tid & 63;
    const int lo = lane & 15;         // A row-slot / B col (o) / C col
    const int hi = lane >> 4;         // k-group 0..3
    const int sr = lo & 7;            // read-side swizzle key (o-row = lo)

    y_lds[tid]       = y[tid];
    y_lds[tid + 256] = y[tid + 256];

    // A fragments (x -> bf16) and mask chunks: built once, live for all 16 g.
    // sigma: frag elem (hi,j): j<4 -> t = tA+j ; j>=4 -> t = tA+16+(j-4)
    bf16x8 afrag[2][2];               // [window W][b-half]
    f32x4 mka[2], mkb[2];
    const int tbase = wv * 64;
#pragma unroll
    for (int W = 0; W < 2; ++W) {
        const int ta = tbase + W * 32 + hi * 4;
        const int tb = ta + 16;
        f32x4 xa0 = *(const f32x4*)(x + ((size_t)lo * Nq + n) * Tq + ta);
        f32x4 xb0 = *(const f32x4*)(x + ((size_t)lo * Nq + n) * Tq + tb);
        f32x4 xa1 = *(const f32x4*)(x + ((size_t)(lo + 16) * Nq + n) * Tq + ta);
        f32x4 xb1 = *(const f32x4*)(x + ((size_t)(lo + 16) * Nq + n) * Tq + tb);
        mka[W] = *(const f32x4*)(mask + (size_t)(o0 + lo) * Tq + ta);
        mkb[W] = *(const f32x4*)(mask + (size_t)(o0 + lo) * Tq + tb);
#pragma unroll
        for (int j = 0; j < 4; ++j) {
            afrag[W][0][j]     = f2bf(xa0[j]);
            afrag[W][0][j + 4] = f2bf(xb0[j]);
            afrag[W][1][j]     = f2bf(xa1[j]);
            afrag[W][1][j + 4] = f2bf(xb1[j]);
        }
    }

    const size_t GS = (size_t)Oq * Nq * Tq;   // g-stride in floats
    const float* wsrc[4];
#pragma unroll
    for (int q = 0; q < 4; ++q) {
        const int r = wv * 4 + q;
        wsrc[q] = w + ((size_t)(o0 + r) * Nq + n) * Tq + ((lane ^ (r & 7)) << 2);
    }

    // y_lds visibility + drain all prologue VMEM (x/mask consumed above).
    __syncthreads();

    // prologue issues: g=0 -> buf0, g=1 -> buf1 (4 instr each per wave)
#pragma unroll
    for (int q = 0; q < 4; ++q)
        gld_lds16(wsrc[q], &wbuf[0][(wv * 4 + q) * 256]);
#pragma unroll
    for (int q = 0; q < 4; ++q)
        gld_lds16(wsrc[q] + GS, &wbuf[1][(wv * 4 + q) * 256]);
    asm volatile("s_waitcnt vmcnt(4)" ::: "memory");   // g=0 landed, g=1 flying
    __builtin_amdgcn_s_barrier();

    f32x4 facc0 = {0.f, 0.f, 0.f, 0.f};   // b = 0..15 rows (y-weighted)
    f32x4 facc1 = {0.f, 0.f, 0.f, 0.f};   // b = 16..31 rows

#pragma unroll
    for (int g = 0; g < 16; ++g) {
        const int cb = g % 3;
        if (g < 14) {   // issue prefetch for g+2
            const int pb = (g + 2) % 3;
#pragma unroll
            for (int q = 0; q < 4; ++q)
                gld_lds16(wsrc[q] + (size_t)(g + 2) * GS,
                          &wbuf[pb][(wv * 4 + q) * 256]);
        }

        f32x4 acc0 = {0.f, 0.f, 0.f, 0.f};
        f32x4 acc1 = {0.f, 0.f, 0.f, 0.f};
#pragma unroll
        for (int W = 0; W < 2; ++W) {
            const int c0 = wv * 16 + W * 8 + hi;   // logical 16B-chunk in row
            f32x4 wa4 = *(const f32x4*)&wbuf[cb][lo * 256 + ((c0 ^ sr) << 2)];
            f32x4 wb4 = *(const f32x4*)&wbuf[cb][lo * 256 + (((c0 + 4) ^ sr) << 2)];
            bf16x8 bfr;
#pragma unroll
            for (int j = 0; j < 4; ++j) {
                bfr[j]     = f2bf(wa4[j] * mka[W][j]);
                bfr[j + 4] = f2bf(wb4[j] * mkb[W][j]);
            }
            acc0 = __builtin_amdgcn_mfma_f32_16x16x32_bf16(afrag[W][0], bfr, acc0, 0, 0, 0);
            acc1 = __builtin_amdgcn_mfma_f32_16x16x32_bf16(afrag[W][1], bfr, acc1, 0, 0, 0);
        }

        // apply y[b,g] to this g's f32 partial (C row b = half*16 + hi*4 + i)
#pragma unroll
        for (int i = 0; i < 4; ++i) {
            facc0[i] += y_lds[(hi * 4 + i) * Gq + g] * acc0[i];
            facc1[i] += y_lds[(16 + hi * 4 + i) * Gq + g] * acc1[i];
        }

        if (g < 14) {
            // g+1's rows landed (only the 4 newest, g+2's, may still fly)
            asm volatile("s_waitcnt vmcnt(4)" ::: "memory");
            __builtin_amdgcn_s_barrier();
        } else if (g == 14) {
            asm volatile("s_waitcnt vmcnt(0)" ::: "memory");   // drain g=15's
            __builtin_amdgcn_s_barrier();
        }
        // g == 15: no wait; reduction barrier below protects the overlay
    }

    // cross-wave (t-split) reduction; overlay red[4][32][16] on wbuf[0].
    // __syncthreads (not raw barrier): need lgkmcnt(0) release for the
    // cross-wave LDS read-after-write.
    __syncthreads();
    float (*red)[32][16] = (float (*)[32][16]) & wbuf[0][0];
#pragma unroll
    for (int i = 0; i < 4; ++i) {
        red[wv][hi * 4 + i][lo]      = facc0[i];
        red[wv][16 + hi * 4 + i][lo] = facc1[i];
    }
    __syncthreads();

    // 512 outputs (32 b x 16 o), 256 threads -> 2 each; sum 4 wave-partials
#pragma unroll
    for (int s = 0; s < 2; ++s) {
        const int idx = tid + s * 256;
        const int b  = idx >> 4;
        const int oo = idx & 15;
        const float v = red[0][b][oo] + red[1][b][oo] + red[2][b][oo] + red[3][b][oo]
                      + bias[o0 + oo];
        out[((size_t)b * Nq + n) * Oq + o0 + oo] = v;
    }
}

extern "C" void kernel_launch(void* const* d_in, const int* in_sizes, int n_in,
                              void* d_out, int out_size, void* d_ws, size_t ws_size,
                              hipStream_t stream) {
    const float* x    = (const float*)d_in[0];
    const float* y    = (const float*)d_in[1];
    const float* w    = (const float*)d_in[2];
    const float* mask = (const float*)d_in[3];
    const float* bias = (const float*)d_in[4];
    float* out = (float*)d_out;

    dim3 grid(Nq * (Oq / 16));  // 88 n-slices * 16 o-tiles = 1408 blocks
    dim3 block(256);
    hipLaunchKernelGGL(mlm_mfma5, grid, block, 0, stream, x, y, w, mask, bias, out);
}

// Round 6
// 74.349 us; speedup vs baseline: 1.9210x; 1.8364x over previous
//
#include <hip/hip_runtime.h>

// Sizes (fixed by the reference)
#define Bq 32
#define Gq 16
#define Oq 256
#define Nq 88
#define Tq 256

typedef short bf16x8 __attribute__((ext_vector_type(8)));   // 8 bf16 in 4 VGPRs
typedef float f32x4 __attribute__((ext_vector_type(4)));

static __device__ __forceinline__ short f2bf(float f) {
    return __builtin_bit_cast(short, (__bf16)f);  // RNE convert, bits as short
}

// Async global->LDS, 16B per lane. Dest = wave-uniform base + lane*16 (linear).
// Source is per-lane -> swizzle applied on the GLOBAL side (rule 21).
static __device__ __forceinline__ void gld_lds16(const float* src, float* lds_dst) {
    __builtin_amdgcn_global_load_lds(
        (const __attribute__((address_space(1))) void*)src,
        (__attribute__((address_space(3))) void*)lds_dst, 16, 0, 0);
}

// out[b,n,o] = sum_{g,t} x[b,n,t] * y[b,g] * w[g,o,n,t] * mask[o,t] + bias[o]
//
// R6 = R2 (75.2us baseline) + ONE change: counted-vmcnt pipeline (T3/T4).
//  - 3 x 16KB weight slabs, prefetch distance 2 (issue g+2 while computing g).
//  - In-loop wait is vmcnt(4) (own g+2 rows still flying) + raw s_barrier;
//    NEVER drain to 0 until g=14. R2's vmcnt(0)+__syncthreads drain left each
//    block with zero outstanding requests every iteration -> 79% of peak.
//  - g-loop pinned unroll-1; staging pointers advanced incrementally (+GS)
//    to avoid R5's address-precompute / unroll blowup.
//  - __syncthreads BEFORE the first gld_lds drains all prologue VMEM, making
//    the in-loop per-wave vmcnt counts exact (4 issued per iteration).
//  - XOR swizzle chunk^=(o-row&7) on global source and LDS read (rule 21).
//  - y[b,g] applied per-g to the f32 MFMA partial (same numerics as R2).
__global__ __launch_bounds__(256, 3)
void mlm_mfma6(const float* __restrict__ x, const float* __restrict__ y,
               const float* __restrict__ w, const float* __restrict__ mask,
               const float* __restrict__ bias, float* __restrict__ out) {
    __shared__ float wbuf[3][4096];   // 3 x 16KB: [16 rows(o)][64 chunks x 4 floats]
    __shared__ float y_lds[512];      // y[b][g] row-major

    const int bid = blockIdx.x;
    const int n  = bid >> 4;          // 0..87
    const int o0 = (bid & 15) << 4;   // o-tile base

    const int tid  = threadIdx.x;
    const int wv   = tid >> 6;        // 0..3 -> t-range [wv*64, wv*64+64)
    const int lane = tid & 63;
    const int lo = lane & 15;         // A row-slot / B col (o) / C col
    const int hi = lane >> 4;         // k-group 0..3
    const int sr = lo & 7;            // read-side swizzle key (o-row = lo)

    y_lds[tid]       = y[tid];
    y_lds[tid + 256] = y[tid + 256];

    // A fragments (x -> bf16) and mask chunks: built once, live for all 16 g.
    // sigma: frag elem (hi,j): j<4 -> t = tA+j ; j>=4 -> t = tA+16+(j-4)
    bf16x8 afrag[2][2];               // [window W][b-half]
    f32x4 mka[2], mkb[2];
    const int tbase = wv * 64;
#pragma unroll
    for (int W = 0; W < 2; ++W) {
        const int ta = tbase + W * 32 + hi * 4;
        const int tb = ta + 16;
        f32x4 xa0 = *(const f32x4*)(x + ((size_t)lo * Nq + n) * Tq + ta);
        f32x4 xb0 = *(const f32x4*)(x + ((size_t)lo * Nq + n) * Tq + tb);
        f32x4 xa1 = *(const f32x4*)(x + ((size_t)(lo + 16) * Nq + n) * Tq + ta);
        f32x4 xb1 = *(const f32x4*)(x + ((size_t)(lo + 16) * Nq + n) * Tq + tb);
        mka[W] = *(const f32x4*)(mask + (size_t)(o0 + lo) * Tq + ta);
        mkb[W] = *(const f32x4*)(mask + (size_t)(o0 + lo) * Tq + tb);
#pragma unroll
        for (int j = 0; j < 4; ++j) {
            afrag[W][0][j]     = f2bf(xa0[j]);
            afrag[W][0][j + 4] = f2bf(xb0[j]);
            afrag[W][1][j]     = f2bf(xa1[j]);
            afrag[W][1][j + 4] = f2bf(xb1[j]);
        }
    }

    const size_t GS = (size_t)Oq * Nq * Tq;   // g-stride in floats
    const float* wsrc[4];
#pragma unroll
    for (int q = 0; q < 4; ++q) {
        const int r = wv * 4 + q;
        wsrc[q] = w + ((size_t)(o0 + r) * Nq + n) * Tq + ((lane ^ (r & 7)) << 2);
    }

    // y_lds visibility AND full drain of prologue VMEM (x/mask/y) -> the
    // in-loop vmcnt counts below are exact.
    __syncthreads();

    // prologue issues: g=0 -> buf0, g=1 -> buf1 (4 instr each per wave)
#pragma unroll
    for (int q = 0; q < 4; ++q)
        gld_lds16(wsrc[q], &wbuf[0][(wv * 4 + q) * 256]);
#pragma unroll
    for (int q = 0; q < 4; ++q)
        gld_lds16(wsrc[q] + GS, &wbuf[1][(wv * 4 + q) * 256]);
    asm volatile("s_waitcnt vmcnt(4)" ::: "memory");   // g=0 landed, g=1 flying
    __builtin_amdgcn_s_barrier();
    __builtin_amdgcn_sched_barrier(0);

    // running prefetch pointers (incremental: no per-iter (g+2)*GS remat)
    const float* wpre[4];
#pragma unroll
    for (int q = 0; q < 4; ++q) wpre[q] = wsrc[q] + 2 * GS;

    f32x4 facc0 = {0.f, 0.f, 0.f, 0.f};   // b = 0..15 rows (y-weighted)
    f32x4 facc1 = {0.f, 0.f, 0.f, 0.f};   // b = 16..31 rows

    int cb = 0;   // buffer holding g's slab
    int pb = 2;   // buffer to prefetch g+2 into
#pragma unroll 1
    for (int g = 0; g < 16; ++g) {
        if (g < 14) {   // issue prefetch for g+2
#pragma unroll
            for (int q = 0; q < 4; ++q) {
                gld_lds16(wpre[q], &wbuf[pb][(wv * 4 + q) * 256]);
                wpre[q] += GS;
            }
        }

        const float* wrow = &wbuf[cb][lo * 256];
        f32x4 acc0 = {0.f, 0.f, 0.f, 0.f};
        f32x4 acc1 = {0.f, 0.f, 0.f, 0.f};
#pragma unroll
        for (int W = 0; W < 2; ++W) {
            const int c0 = wv * 16 + W * 8 + hi;   // logical 16B-chunk in row
            f32x4 wa4 = *(const f32x4*)(wrow + ((c0 ^ sr) << 2));
            f32x4 wb4 = *(const f32x4*)(wrow + (((c0 + 4) ^ sr) << 2));
            bf16x8 bfr;
#pragma unroll
            for (int j = 0; j < 4; ++j) {
                bfr[j]     = f2bf(wa4[j] * mka[W][j]);
                bfr[j + 4] = f2bf(wb4[j] * mkb[W][j]);
            }
            acc0 = __builtin_amdgcn_mfma_f32_16x16x32_bf16(afrag[W][0], bfr, acc0, 0, 0, 0);
            acc1 = __builtin_amdgcn_mfma_f32_16x16x32_bf16(afrag[W][1], bfr, acc1, 0, 0, 0);
        }

        // apply y[b,g] to this g's f32 partial (C row b = half*16 + hi*4 + i)
#pragma unroll
        for (int i = 0; i < 4; ++i) {
            facc0[i] += y_lds[(hi * 4 + i) * Gq + g] * acc0[i];
            facc1[i] += y_lds[(16 + hi * 4 + i) * Gq + g] * acc1[i];
        }

        if (g < 14) {
            // g+1's rows landed; only the 4 newest (g+2's) may still fly
            asm volatile("s_waitcnt vmcnt(4)" ::: "memory");
            __builtin_amdgcn_s_barrier();
            __builtin_amdgcn_sched_barrier(0);
        } else if (g == 14) {
            asm volatile("s_waitcnt vmcnt(0)" ::: "memory");   // drain g=15's
            __builtin_amdgcn_s_barrier();
            __builtin_amdgcn_sched_barrier(0);
        }
        // g == 15: no wait; epilogue __syncthreads protects the overlay

        cb = (cb == 2) ? 0 : cb + 1;
        pb = (pb == 2) ? 0 : pb + 1;
    }

    // cross-wave (t-split) reduction; overlay red[4][32][16] on wbuf[0].
    // __syncthreads: all waves done reading wbuf[0] (g=15 reads buf 0) before
    // overlay writes, plus lgkmcnt release for cross-wave LDS visibility.
    __syncthreads();
    float (*red)[32][16] = (float (*)[32][16]) & wbuf[0][0];
#pragma unroll
    for (int i = 0; i < 4; ++i) {
        red[wv][hi * 4 + i][lo]      = facc0[i];
        red[wv][16 + hi * 4 + i][lo] = facc1[i];
    }
    __syncthreads();

    // 512 outputs (32 b x 16 o), 256 threads -> 2 each; sum 4 wave-partials
#pragma unroll
    for (int s = 0; s < 2; ++s) {
        const int idx = tid + s * 256;
        const int b  = idx >> 4;
        const int oo = idx & 15;
        const float v = red[0][b][oo] + red[1][b][oo] + red[2][b][oo] + red[3][b][oo]
                      + bias[o0 + oo];
        out[((size_t)b * Nq + n) * Oq + o0 + oo] = v;
    }
}

extern "C" void kernel_launch(void* const* d_in, const int* in_sizes, int n_in,
                              void* d_out, int out_size, void* d_ws, size_t ws_size,
                              hipStream_t stream) {
    const float* x    = (const float*)d_in[0];
    const float* y    = (const float*)d_in[1];
    const float* w    = (const float*)d_in[2];
    const float* mask = (const float*)d_in[3];
    const float* bias = (const float*)d_in[4];
    float* out = (float*)d_out;

    dim3 grid(Nq * (Oq / 16));  // 88 n-slices * 16 o-tiles = 1408 blocks
    dim3 block(256);
    hipLaunchKernelGGL(mlm_mfma6, grid, block, 0, stream, x, y, w, mask, bias, out);
}

// Round 7
// 69.911 us; speedup vs baseline: 2.0429x; 1.0635x over previous
//
#include <hip/hip_runtime.h>

// Sizes (fixed by the reference)
#define Bq 32
#define Gq 16
#define Oq 256
#define Nq 88
#define Tq 256

typedef short bf16x8 __attribute__((ext_vector_type(8)));   // 8 bf16 in 4 VGPRs
typedef float f32x4 __attribute__((ext_vector_type(4)));

static __device__ __forceinline__ short f2bf(float f) {
    return __builtin_bit_cast(short, (__bf16)f);  // RNE convert, bits as short
}

// Async global->LDS, 16B per lane. Dest = wave-uniform base + lane*16 (linear).
// Source is per-lane -> swizzle applied on the GLOBAL side (rule 21).
// aux = CPol: NT=2 (non-temporal / no-allocate streaming) for the read-once
// weight tensor: skips LLC fill/evict work and stops evicting x/mask.
static __device__ __forceinline__ void gld_lds16_nt(const float* src, float* lds_dst) {
    __builtin_amdgcn_global_load_lds(
        (const __attribute__((address_space(1))) void*)src,
        (__attribute__((address_space(3))) void*)lds_dst, 16, 0, /*aux=NT*/ 2);
}

// out[b,n,o] = sum_{g,t} x[b,n,t] * y[b,g] * w[g,o,n,t] * mask[o,t] + bias[o]
//
// R7 = R6 (74.3us) + ONE change: non-temporal cache policy on weight staging.
//  - 3 x 16KB weight slabs, prefetch distance 2, counted vmcnt(4) + raw
//    s_barrier (never drain to 0 until g=14).
//  - Weight is read exactly once device-wide: NT stops it from churning the
//    256MB LLC (alloc/evict path) and from evicting the reused x/mask.
//  - All other structure identical to R6 for clean attribution.
__global__ __launch_bounds__(256, 3)
void mlm_mfma7(const float* __restrict__ x, const float* __restrict__ y,
               const float* __restrict__ w, const float* __restrict__ mask,
               const float* __restrict__ bias, float* __restrict__ out) {
    __shared__ float wbuf[3][4096];   // 3 x 16KB: [16 rows(o)][64 chunks x 4 floats]
    __shared__ float y_lds[512];      // y[b][g] row-major

    const int bid = blockIdx.x;
    const int n  = bid >> 4;          // 0..87
    const int o0 = (bid & 15) << 4;   // o-tile base

    const int tid  = threadIdx.x;
    const int wv   = tid >> 6;        // 0..3 -> t-range [wv*64, wv*64+64)
    const int lane = tid & 63;
    const int lo = lane & 15;         // A row-slot / B col (o) / C col
    const int hi = lane >> 4;         // k-group 0..3
    const int sr = lo & 7;            // read-side swizzle key (o-row = lo)

    y_lds[tid]       = y[tid];
    y_lds[tid + 256] = y[tid + 256];

    // A fragments (x -> bf16) and mask chunks: built once, live for all 16 g.
    // sigma: frag elem (hi,j): j<4 -> t = tA+j ; j>=4 -> t = tA+16+(j-4)
    bf16x8 afrag[2][2];               // [window W][b-half]
    f32x4 mka[2], mkb[2];
    const int tbase = wv * 64;
#pragma unroll
    for (int W = 0; W < 2; ++W) {
        const int ta = tbase + W * 32 + hi * 4;
        const int tb = ta + 16;
        f32x4 xa0 = *(const f32x4*)(x + ((size_t)lo * Nq + n) * Tq + ta);
        f32x4 xb0 = *(const f32x4*)(x + ((size_t)lo * Nq + n) * Tq + tb);
        f32x4 xa1 = *(const f32x4*)(x + ((size_t)(lo + 16) * Nq + n) * Tq + ta);
        f32x4 xb1 = *(const f32x4*)(x + ((size_t)(lo + 16) * Nq + n) * Tq + tb);
        mka[W] = *(const f32x4*)(mask + (size_t)(o0 + lo) * Tq + ta);
        mkb[W] = *(const f32x4*)(mask + (size_t)(o0 + lo) * Tq + tb);
#pragma unroll
        for (int j = 0; j < 4; ++j) {
            afrag[W][0][j]     = f2bf(xa0[j]);
            afrag[W][0][j + 4] = f2bf(xb0[j]);
            afrag[W][1][j]     = f2bf(xa1[j]);
            afrag[W][1][j + 4] = f2bf(xb1[j]);
        }
    }

    const size_t GS = (size_t)Oq * Nq * Tq;   // g-stride in floats
    const float* wsrc[4];
#pragma unroll
    for (int q = 0; q < 4; ++q) {
        const int r = wv * 4 + q;
        wsrc[q] = w + ((size_t)(o0 + r) * Nq + n) * Tq + ((lane ^ (r & 7)) << 2);
    }

    // y_lds visibility AND full drain of prologue VMEM (x/mask/y) -> the
    // in-loop vmcnt counts below are exact.
    __syncthreads();

    // prologue issues: g=0 -> buf0, g=1 -> buf1 (4 instr each per wave)
#pragma unroll
    for (int q = 0; q < 4; ++q)
        gld_lds16_nt(wsrc[q], &wbuf[0][(wv * 4 + q) * 256]);
#pragma unroll
    for (int q = 0; q < 4; ++q)
        gld_lds16_nt(wsrc[q] + GS, &wbuf[1][(wv * 4 + q) * 256]);
    asm volatile("s_waitcnt vmcnt(4)" ::: "memory");   // g=0 landed, g=1 flying
    __builtin_amdgcn_s_barrier();
    __builtin_amdgcn_sched_barrier(0);

    // running prefetch pointers (incremental: no per-iter (g+2)*GS remat)
    const float* wpre[4];
#pragma unroll
    for (int q = 0; q < 4; ++q) wpre[q] = wsrc[q] + 2 * GS;

    f32x4 facc0 = {0.f, 0.f, 0.f, 0.f};   // b = 0..15 rows (y-weighted)
    f32x4 facc1 = {0.f, 0.f, 0.f, 0.f};   // b = 16..31 rows

    int cb = 0;   // buffer holding g's slab
    int pb = 2;   // buffer to prefetch g+2 into
#pragma unroll 1
    for (int g = 0; g < 16; ++g) {
        if (g < 14) {   // issue prefetch for g+2
#pragma unroll
            for (int q = 0; q < 4; ++q) {
                gld_lds16_nt(wpre[q], &wbuf[pb][(wv * 4 + q) * 256]);
                wpre[q] += GS;
            }
        }

        const float* wrow = &wbuf[cb][lo * 256];
        f32x4 acc0 = {0.f, 0.f, 0.f, 0.f};
        f32x4 acc1 = {0.f, 0.f, 0.f, 0.f};
#pragma unroll
        for (int W = 0; W < 2; ++W) {
            const int c0 = wv * 16 + W * 8 + hi;   // logical 16B-chunk in row
            f32x4 wa4 = *(const f32x4*)(wrow + ((c0 ^ sr) << 2));
            f32x4 wb4 = *(const f32x4*)(wrow + (((c0 + 4) ^ sr) << 2));
            bf16x8 bfr;
#pragma unroll
            for (int j = 0; j < 4; ++j) {
                bfr[j]     = f2bf(wa4[j] * mka[W][j]);
                bfr[j + 4] = f2bf(wb4[j] * mkb[W][j]);
            }
            acc0 = __builtin_amdgcn_mfma_f32_16x16x32_bf16(afrag[W][0], bfr, acc0, 0, 0, 0);
            acc1 = __builtin_amdgcn_mfma_f32_16x16x32_bf16(afrag[W][1], bfr, acc1, 0, 0, 0);
        }

        // apply y[b,g] to this g's f32 partial (C row b = half*16 + hi*4 + i)
#pragma unroll
        for (int i = 0; i < 4; ++i) {
            facc0[i] += y_lds[(hi * 4 + i) * Gq + g] * acc0[i];
            facc1[i] += y_lds[(16 + hi * 4 + i) * Gq + g] * acc1[i];
        }

        if (g < 14) {
            // g+1's rows landed; only the 4 newest (g+2's) may still fly
            asm volatile("s_waitcnt vmcnt(4)" ::: "memory");
            __builtin_amdgcn_s_barrier();
            __builtin_amdgcn_sched_barrier(0);
        } else if (g == 14) {
            asm volatile("s_waitcnt vmcnt(0)" ::: "memory");   // drain g=15's
            __builtin_amdgcn_s_barrier();
            __builtin_amdgcn_sched_barrier(0);
        }
        // g == 15: no wait; epilogue __syncthreads protects the overlay

        cb = (cb == 2) ? 0 : cb + 1;
        pb = (pb == 2) ? 0 : pb + 1;
    }

    // cross-wave (t-split) reduction; overlay red[4][32][16] on wbuf[0].
    __syncthreads();
    float (*red)[32][16] = (float (*)[32][16]) & wbuf[0][0];
#pragma unroll
    for (int i = 0; i < 4; ++i) {
        red[wv][hi * 4 + i][lo]      = facc0[i];
        red[wv][16 + hi * 4 + i][lo] = facc1[i];
    }
    __syncthreads();

    // 512 outputs (32 b x 16 o), 256 threads -> 2 each; sum 4 wave-partials
#pragma unroll
    for (int s = 0; s < 2; ++s) {
        const int idx = tid + s * 256;
        const int b  = idx >> 4;
        const int oo = idx & 15;
        const float v = red[0][b][oo] + red[1][b][oo] + red[2][b][oo] + red[3][b][oo]
                      + bias[o0 + oo];
        out[((size_t)b * Nq + n) * Oq + o0 + oo] = v;
    }
}

extern "C" void kernel_launch(void* const* d_in, const int* in_sizes, int n_in,
                              void* d_out, int out_size, void* d_ws, size_t ws_size,
                              hipStream_t stream) {
    const float* x    = (const float*)d_in[0];
    const float* y    = (const float*)d_in[1];
    const float* w    = (const float*)d_in[2];
    const float* mask = (const float*)d_in[3];
    const float* bias = (const float*)d_in[4];
    float* out = (float*)d_out;

    dim3 grid(Nq * (Oq / 16));  // 88 n-slices * 16 o-tiles = 1408 blocks
    dim3 block(256);
    hipLaunchKernelGGL(mlm_mfma7, grid, block, 0, stream, x, y, w, mask, bias, out);
}

// Round 8
// 69.881 us; speedup vs baseline: 2.0438x; 1.0004x over previous
//
#include <hip/hip_runtime.h>

// Sizes (fixed by the reference)
#define Bq 32
#define Gq 16
#define Oq 256
#define Nq 88
#define Tq 256

typedef short bf16x8 __attribute__((ext_vector_type(8)));   // 8 bf16 in 4 VGPRs
typedef float f32x4 __attribute__((ext_vector_type(4)));

static __device__ __forceinline__ short f2bf(float f) {
    return __builtin_bit_cast(short, (__bf16)f);  // RNE convert, bits as short
}

// Async global->LDS, 16B per lane. Dest = wave-uniform base + lane*16 (linear).
// Source is per-lane -> swizzle applied on the GLOBAL side (rule 21).
// aux = CPol: NT(2) | SC1(16) = 18 -> non-temporal at BOTH the MALL and L2
// levels (gfx940+ CPol: SC0=1, NT=2, SC1=16). Weight lines are read exactly
// once by exactly one block: any cache allocation is pure fill/evict overhead
// and evicts the genuinely-reused x/mask. NT alone (R7) = +6.3%.
static __device__ __forceinline__ void gld_lds16_nt(const float* src, float* lds_dst) {
    __builtin_amdgcn_global_load_lds(
        (const __attribute__((address_space(1))) void*)src,
        (__attribute__((address_space(3))) void*)lds_dst, 16, 0, /*aux=NT|SC1*/ 18);
}

// out[b,n,o] = sum_{g,t} x[b,n,t] * y[b,g] * w[g,o,n,t] * mask[o,t] + bias[o]
//
// R8 = R7 (69.9us) + ONE change: SC1 added to the weight-staging cache policy
// (no-allocate in L2 as well as MALL). Everything else identical to R7.
//  - 3 x 16KB weight slabs, prefetch distance 2, counted vmcnt(4) + raw
//    s_barrier (never drain to 0 until g=14).
//  - XOR swizzle chunk^=(o-row&7) on global source and LDS read (rule 21).
//  - y[b,g] applied per-g to the f32 MFMA partial.
__global__ __launch_bounds__(256, 3)
void mlm_mfma8(const float* __restrict__ x, const float* __restrict__ y,
               const float* __restrict__ w, const float* __restrict__ mask,
               const float* __restrict__ bias, float* __restrict__ out) {
    __shared__ float wbuf[3][4096];   // 3 x 16KB: [16 rows(o)][64 chunks x 4 floats]
    __shared__ float y_lds[512];      // y[b][g] row-major

    const int bid = blockIdx.x;
    const int n  = bid >> 4;          // 0..87
    const int o0 = (bid & 15) << 4;   // o-tile base

    const int tid  = threadIdx.x;
    const int wv   = tid >> 6;        // 0..3 -> t-range [wv*64, wv*64+64)
    const int lane = tid & 63;
    const int lo = lane & 15;         // A row-slot / B col (o) / C col
    const int hi = lane >> 4;         // k-group 0..3
    const int sr = lo & 7;            // read-side swizzle key (o-row = lo)

    y_lds[tid]       = y[tid];
    y_lds[tid + 256] = y[tid + 256];

    // A fragments (x -> bf16) and mask chunks: built once, live for all 16 g.
    // sigma: frag elem (hi,j): j<4 -> t = tA+j ; j>=4 -> t = tA+16+(j-4)
    bf16x8 afrag[2][2];               // [window W][b-half]
    f32x4 mka[2], mkb[2];
    const int tbase = wv * 64;
#pragma unroll
    for (int W = 0; W < 2; ++W) {
        const int ta = tbase + W * 32 + hi * 4;
        const int tb = ta + 16;
        f32x4 xa0 = *(const f32x4*)(x + ((size_t)lo * Nq + n) * Tq + ta);
        f32x4 xb0 = *(const f32x4*)(x + ((size_t)lo * Nq + n) * Tq + tb);
        f32x4 xa1 = *(const f32x4*)(x + ((size_t)(lo + 16) * Nq + n) * Tq + ta);
        f32x4 xb1 = *(const f32x4*)(x + ((size_t)(lo + 16) * Nq + n) * Tq + tb);
        mka[W] = *(const f32x4*)(mask + (size_t)(o0 + lo) * Tq + ta);
        mkb[W] = *(const f32x4*)(mask + (size_t)(o0 + lo) * Tq + tb);
#pragma unroll
        for (int j = 0; j < 4; ++j) {
            afrag[W][0][j]     = f2bf(xa0[j]);
            afrag[W][0][j + 4] = f2bf(xb0[j]);
            afrag[W][1][j]     = f2bf(xa1[j]);
            afrag[W][1][j + 4] = f2bf(xb1[j]);
        }
    }

    const size_t GS = (size_t)Oq * Nq * Tq;   // g-stride in floats
    const float* wsrc[4];
#pragma unroll
    for (int q = 0; q < 4; ++q) {
        const int r = wv * 4 + q;
        wsrc[q] = w + ((size_t)(o0 + r) * Nq + n) * Tq + ((lane ^ (r & 7)) << 2);
    }

    // y_lds visibility AND full drain of prologue VMEM (x/mask/y) -> the
    // in-loop vmcnt counts below are exact.
    __syncthreads();

    // prologue issues: g=0 -> buf0, g=1 -> buf1 (4 instr each per wave)
#pragma unroll
    for (int q = 0; q < 4; ++q)
        gld_lds16_nt(wsrc[q], &wbuf[0][(wv * 4 + q) * 256]);
#pragma unroll
    for (int q = 0; q < 4; ++q)
        gld_lds16_nt(wsrc[q] + GS, &wbuf[1][(wv * 4 + q) * 256]);
    asm volatile("s_waitcnt vmcnt(4)" ::: "memory");   // g=0 landed, g=1 flying
    __builtin_amdgcn_s_barrier();
    __builtin_amdgcn_sched_barrier(0);

    // running prefetch pointers (incremental: no per-iter (g+2)*GS remat)
    const float* wpre[4];
#pragma unroll
    for (int q = 0; q < 4; ++q) wpre[q] = wsrc[q] + 2 * GS;

    f32x4 facc0 = {0.f, 0.f, 0.f, 0.f};   // b = 0..15 rows (y-weighted)
    f32x4 facc1 = {0.f, 0.f, 0.f, 0.f};   // b = 16..31 rows

    int cb = 0;   // buffer holding g's slab
    int pb = 2;   // buffer to prefetch g+2 into
#pragma unroll 1
    for (int g = 0; g < 16; ++g) {
        if (g < 14) {   // issue prefetch for g+2
#pragma unroll
            for (int q = 0; q < 4; ++q) {
                gld_lds16_nt(wpre[q], &wbuf[pb][(wv * 4 + q) * 256]);
                wpre[q] += GS;
            }
        }

        const float* wrow = &wbuf[cb][lo * 256];
        f32x4 acc0 = {0.f, 0.f, 0.f, 0.f};
        f32x4 acc1 = {0.f, 0.f, 0.f, 0.f};
#pragma unroll
        for (int W = 0; W < 2; ++W) {
            const int c0 = wv * 16 + W * 8 + hi;   // logical 16B-chunk in row
            f32x4 wa4 = *(const f32x4*)(wrow + ((c0 ^ sr) << 2));
            f32x4 wb4 = *(const f32x4*)(wrow + (((c0 + 4) ^ sr) << 2));
            bf16x8 bfr;
#pragma unroll
            for (int j = 0; j < 4; ++j) {
                bfr[j]     = f2bf(wa4[j] * mka[W][j]);
                bfr[j + 4] = f2bf(wb4[j] * mkb[W][j]);
            }
            acc0 = __builtin_amdgcn_mfma_f32_16x16x32_bf16(afrag[W][0], bfr, acc0, 0, 0, 0);
            acc1 = __builtin_amdgcn_mfma_f32_16x16x32_bf16(afrag[W][1], bfr, acc1, 0, 0, 0);
        }

        // apply y[b,g] to this g's f32 partial (C row b = half*16 + hi*4 + i)
#pragma unroll
        for (int i = 0; i < 4; ++i) {
            facc0[i] += y_lds[(hi * 4 + i) * Gq + g] * acc0[i];
            facc1[i] += y_lds[(16 + hi * 4 + i) * Gq + g] * acc1[i];
        }

        if (g < 14) {
            // g+1's rows landed; only the 4 newest (g+2's) may still fly
            asm volatile("s_waitcnt vmcnt(4)" ::: "memory");
            __builtin_amdgcn_s_barrier();
            __builtin_amdgcn_sched_barrier(0);
        } else if (g == 14) {
            asm volatile("s_waitcnt vmcnt(0)" ::: "memory");   // drain g=15's
            __builtin_amdgcn_s_barrier();
            __builtin_amdgcn_sched_barrier(0);
        }
        // g == 15: no wait; epilogue __syncthreads protects the overlay

        cb = (cb == 2) ? 0 : cb + 1;
        pb = (pb == 2) ? 0 : pb + 1;
    }

    // cross-wave (t-split) reduction; overlay red[4][32][16] on wbuf[0].
    __syncthreads();
    float (*red)[32][16] = (float (*)[32][16]) & wbuf[0][0];
#pragma unroll
    for (int i = 0; i < 4; ++i) {
        red[wv][hi * 4 + i][lo]      = facc0[i];
        red[wv][16 + hi * 4 + i][lo] = facc1[i];
    }
    __syncthreads();

    // 512 outputs (32 b x 16 o), 256 threads -> 2 each; sum 4 wave-partials
#pragma unroll
    for (int s = 0; s < 2; ++s) {
        const int idx = tid + s * 256;
        const int b  = idx >> 4;
        const int oo = idx & 15;
        const float v = red[0][b][oo] + red[1][b][oo] + red[2][b][oo] + red[3][b][oo]
                      + bias[o0 + oo];
        out[((size_t)b * Nq + n) * Oq + o0 + oo] = v;
    }
}

extern "C" void kernel_launch(void* const* d_in, const int* in_sizes, int n_in,
                              void* d_out, int out_size, void* d_ws, size_t ws_size,
                              hipStream_t stream) {
    const float* x    = (const float*)d_in[0];
    const float* y    = (const float*)d_in[1];
    const float* w    = (const float*)d_in[2];
    const float* mask = (const float*)d_in[3];
    const float* bias = (const float*)d_in[4];
    float* out = (float*)d_out;

    dim3 grid(Nq * (Oq / 16));  // 88 n-slices * 16 o-tiles = 1408 blocks
    dim3 block(256);
    hipLaunchKernelGGL(mlm_mfma8, grid, block, 0, stream, x, y, w, mask, bias, out);
}

// Round 9
// 68.726 us; speedup vs baseline: 2.0782x; 1.0168x over previous
//
#include <hip/hip_runtime.h>

// Sizes (fixed by the reference)
#define Bq 32
#define Gq 16
#define Oq 256
#define Nq 88
#define Tq 256

typedef short bf16x8 __attribute__((ext_vector_type(8)));   // 8 bf16 in 4 VGPRs
typedef float f32x4 __attribute__((ext_vector_type(4)));

static __device__ __forceinline__ short f2bf(float f) {
    return __builtin_bit_cast(short, (__bf16)f);  // RNE convert, bits as short
}

// out[b,n,o] = sum_{g,t} x[b,n,t] * y[b,g] * w[g,o,n,t] * mask[o,t] + bias[o]
//
// R9 = R8 (69.9us) with ONE mechanism swapped: weight staging via plain
// NT global_load_dwordx4 -> VGPR -> ds_write_b128 (T14 split), instead of
// global_load_lds. Tests whether the LDS-direct DMA path's completion rate
// is the 5.4 TB/s wall (the 6.29 TB/s copy ceiling was measured with plain
// loads). Everything else identical to R8:
//  - 2 x 16KB LDS buffers + 2 register tiles (regA=even g, regB=odd g,
//    static indexing), 8 loads in flight, counted vmcnt(4), raw s_barrier.
//  - XOR swizzle now applied on the ds_write ADDRESS (source read linearly);
//    reader side unchanged: physical chunk p of row r holds logical p^(r&7).
//  - y[b,g] applied per-g to the f32 MFMA partial.
__global__ __launch_bounds__(256, 3)
void mlm_mfma9(const float* __restrict__ x, const float* __restrict__ y,
               const float* __restrict__ w, const float* __restrict__ mask,
               const float* __restrict__ bias, float* __restrict__ out) {
    __shared__ float wbuf[2][4096];   // 2 x 16KB: [16 rows(o)][64 chunks x 4 floats]
    __shared__ float y_lds[512];      // y[b][g] row-major

    const int bid = blockIdx.x;
    const int n  = bid >> 4;          // 0..87
    const int o0 = (bid & 15) << 4;   // o-tile base

    const int tid  = threadIdx.x;
    const int wv   = tid >> 6;        // 0..3 -> t-range [wv*64, wv*64+64)
    const int lane = tid & 63;
    const int lo = lane & 15;         // A row-slot / B col (o) / C col
    const int hi = lane >> 4;         // k-group 0..3
    const int sr = lo & 7;            // read-side swizzle key (o-row = lo)

    y_lds[tid]       = y[tid];
    y_lds[tid + 256] = y[tid + 256];

    // A fragments (x -> bf16) and mask chunks: built once, live for all 16 g.
    // sigma: frag elem (hi,j): j<4 -> t = tA+j ; j>=4 -> t = tA+16+(j-4)
    bf16x8 afrag[2][2];               // [window W][b-half]
    f32x4 mka[2], mkb[2];
    const int tbase = wv * 64;
#pragma unroll
    for (int W = 0; W < 2; ++W) {
        const int ta = tbase + W * 32 + hi * 4;
        const int tb = ta + 16;
        f32x4 xa0 = *(const f32x4*)(x + ((size_t)lo * Nq + n) * Tq + ta);
        f32x4 xb0 = *(const f32x4*)(x + ((size_t)lo * Nq + n) * Tq + tb);
        f32x4 xa1 = *(const f32x4*)(x + ((size_t)(lo + 16) * Nq + n) * Tq + ta);
        f32x4 xb1 = *(const f32x4*)(x + ((size_t)(lo + 16) * Nq + n) * Tq + tb);
        mka[W] = *(const f32x4*)(mask + (size_t)(o0 + lo) * Tq + ta);
        mkb[W] = *(const f32x4*)(mask + (size_t)(o0 + lo) * Tq + tb);
#pragma unroll
        for (int j = 0; j < 4; ++j) {
            afrag[W][0][j]     = f2bf(xa0[j]);
            afrag[W][0][j + 4] = f2bf(xb0[j]);
            afrag[W][1][j]     = f2bf(xa1[j]);
            afrag[W][1][j + 4] = f2bf(xb1[j]);
        }
    }

    // linear global sources (lane-th 16B chunk of each 1KB row) + swizzled
    // LDS write addresses: physical chunk lane^(r&7) of row r (buf0 base).
    const size_t GS = (size_t)Oq * Nq * Tq;   // g-stride in floats
    const float* wptr[4];
    float* dwp[4];
#pragma unroll
    for (int q = 0; q < 4; ++q) {
        const int r = wv * 4 + q;
        wptr[q] = w + ((size_t)(o0 + r) * Nq + n) * Tq + (lane << 2);
        dwp[q]  = &wbuf[0][r * 256 + ((lane ^ (r & 7)) << 2)];
    }

    // drain all prologue VMEM (x/mask/y) -> in-loop vmcnt counts are exact
    __syncthreads();

    f32x4 regA[4], regB[4];           // regA: even g, regB: odd g (static)
    // A <- g0 ; B <- g1   (sequential pointer: +GS per issue)
#pragma unroll
    for (int q = 0; q < 4; ++q) {
        regA[q] = __builtin_nontemporal_load((const f32x4*)wptr[q]);
        wptr[q] += GS;
    }
#pragma unroll
    for (int q = 0; q < 4; ++q) {
        regB[q] = __builtin_nontemporal_load((const f32x4*)wptr[q]);
        wptr[q] += GS;
    }
    asm volatile("s_waitcnt vmcnt(4)" ::: "memory");   // g0 landed
#pragma unroll
    for (int q = 0; q < 4; ++q) *(f32x4*)dwp[q] = regA[q];   // buf0 <- g0
#pragma unroll
    for (int q = 0; q < 4; ++q) {                            // A <- g2
        regA[q] = __builtin_nontemporal_load((const f32x4*)wptr[q]);
        wptr[q] += GS;
    }
    asm volatile("s_waitcnt lgkmcnt(0)" ::: "memory");
    __builtin_amdgcn_s_barrier();
    __builtin_amdgcn_sched_barrier(0);

    f32x4 facc0 = {0.f, 0.f, 0.f, 0.f};   // b = 0..15 rows (y-weighted)
    f32x4 facc1 = {0.f, 0.f, 0.f, 0.f};   // b = 16..31 rows

    // compute one g from the given LDS buffer row base, accumulate into facc
    auto compute_g = [&](int g, const float* wrow) {
        f32x4 acc0 = {0.f, 0.f, 0.f, 0.f};
        f32x4 acc1 = {0.f, 0.f, 0.f, 0.f};
#pragma unroll
        for (int W = 0; W < 2; ++W) {
            const int c0 = wv * 16 + W * 8 + hi;   // logical 16B-chunk in row
            f32x4 wa4 = *(const f32x4*)(wrow + ((c0 ^ sr) << 2));
            f32x4 wb4 = *(const f32x4*)(wrow + (((c0 + 4) ^ sr) << 2));
            bf16x8 bfr;
#pragma unroll
            for (int j = 0; j < 4; ++j) {
                bfr[j]     = f2bf(wa4[j] * mka[W][j]);
                bfr[j + 4] = f2bf(wb4[j] * mkb[W][j]);
            }
            acc0 = __builtin_amdgcn_mfma_f32_16x16x32_bf16(afrag[W][0], bfr, acc0, 0, 0, 0);
            acc1 = __builtin_amdgcn_mfma_f32_16x16x32_bf16(afrag[W][1], bfr, acc1, 0, 0, 0);
        }
#pragma unroll
        for (int i = 0; i < 4; ++i) {
            facc0[i] += y_lds[(hi * 4 + i) * Gq + g] * acc0[i];
            facc1[i] += y_lds[(16 + hi * 4 + i) * Gq + g] * acc1[i];
        }
    };

    const float* wrow0 = &wbuf[0][lo * 256];
    const float* wrow1 = &wbuf[1][lo * 256];

#pragma unroll 1
    for (int gp = 0; gp < 7; ++gp) {
        // ---- even g = 2gp from buf0
        compute_g(2 * gp, wrow0);
        asm volatile("s_waitcnt vmcnt(4)" ::: "memory");   // regB (2gp+1) landed
#pragma unroll
        for (int q = 0; q < 4; ++q) *(f32x4*)(dwp[q] + 4096) = regB[q];  // buf1
#pragma unroll
        for (int q = 0; q < 4; ++q) {                      // B <- 2gp+3 (<=15)
            regB[q] = __builtin_nontemporal_load((const f32x4*)wptr[q]);
            wptr[q] += GS;
        }
        asm volatile("s_waitcnt lgkmcnt(0)" ::: "memory");
        __builtin_amdgcn_s_barrier();
        __builtin_amdgcn_sched_barrier(0);

        // ---- odd g = 2gp+1 from buf1
        compute_g(2 * gp + 1, wrow1);
        asm volatile("s_waitcnt vmcnt(4)" ::: "memory");   // regA (2gp+2) landed
#pragma unroll
        for (int q = 0; q < 4; ++q) *(f32x4*)dwp[q] = regA[q];           // buf0
        if (gp < 6) {
#pragma unroll
            for (int q = 0; q < 4; ++q) {                  // A <- 2gp+4 (<=14)
                regA[q] = __builtin_nontemporal_load((const f32x4*)wptr[q]);
                wptr[q] += GS;
            }
        }
        asm volatile("s_waitcnt lgkmcnt(0)" ::: "memory");
        __builtin_amdgcn_s_barrier();
        __builtin_amdgcn_sched_barrier(0);
    }

    // ---- tail: g14 from buf0 (written at gp=6 odd half)
    compute_g(14, wrow0);
    asm volatile("s_waitcnt vmcnt(0)" ::: "memory");       // regB (g15): only 4 left
#pragma unroll
    for (int q = 0; q < 4; ++q) *(f32x4*)(dwp[q] + 4096) = regB[q];      // buf1
    asm volatile("s_waitcnt lgkmcnt(0)" ::: "memory");
    __builtin_amdgcn_s_barrier();
    __builtin_amdgcn_sched_barrier(0);
    // ---- g15 from buf1
    compute_g(15, wrow1);

    // cross-wave (t-split) reduction; overlay red[4][32][16] on wbuf[0].
    __syncthreads();
    float (*red)[32][16] = (float (*)[32][16]) & wbuf[0][0];
#pragma unroll
    for (int i = 0; i < 4; ++i) {
        red[wv][hi * 4 + i][lo]      = facc0[i];
        red[wv][16 + hi * 4 + i][lo] = facc1[i];
    }
    __syncthreads();

    // 512 outputs (32 b x 16 o), 256 threads -> 2 each; sum 4 wave-partials
#pragma unroll
    for (int s = 0; s < 2; ++s) {
        const int idx = tid + s * 256;
        const int b  = idx >> 4;
        const int oo = idx & 15;
        const float v = red[0][b][oo] + red[1][b][oo] + red[2][b][oo] + red[3][b][oo]
                      + bias[o0 + oo];
        out[((size_t)b * Nq + n) * Oq + o0 + oo] = v;
    }
}

extern "C" void kernel_launch(void* const* d_in, const int* in_sizes, int n_in,
                              void* d_out, int out_size, void* d_ws, size_t ws_size,
                              hipStream_t stream) {
    const float* x    = (const float*)d_in[0];
    const float* y    = (const float*)d_in[1];
    const float* w    = (const float*)d_in[2];
    const float* mask = (const float*)d_in[3];
    const float* bias = (const float*)d_in[4];
    float* out = (float*)d_out;

    dim3 grid(Nq * (Oq / 16));  // 88 n-slices * 16 o-tiles = 1408 blocks
    dim3 block(256);
    hipLaunchKernelGGL(mlm_mfma9, grid, block, 0, stream, x, y, w, mask, bias, out);
}